// Round 1
// baseline (897.388 us; speedup 1.0000x reference)
//
#include <hip/hip_runtime.h>
#include <hip/hip_bf16.h>

#define NB 8
#define LIN_SCALE 0.044194173824159216f
#define SCALE 0.014731391274719736f

// ---------------- workspace layout (bytes) ----------------
static constexpr size_t O_XS   = 0;                   // 8*34*34*512 f32 = 18939904 (zero-padded NHWC modulated x)
static constexpr size_t O_OUT1 = 18939904;            // 8*512*4225 bf16 = 34611200 (pre-blur conv output 65x65)
static constexpr size_t O_WR   = O_OUT1 + 34611200;   // 9*512*512 f32 = 9437184 (per-tap [i][o] weights)
static constexpr size_t O_WSQ  = O_WR + 9437184;      // 512*512 f32
static constexpr size_t O_CL   = O_WSQ + 1048576;     // 16*512 f32
static constexpr size_t O_GR   = O_CL + 32768;        // 16*512 f32
static constexpr size_t O_SB   = O_GR + 32768;        // 8*16 f32 (padded)
static constexpr size_t O_ST0  = O_SB + 1024;         // 8*512 f32
static constexpr size_t O_STS  = O_ST0 + 16384;       // st*scale
static constexpr size_t O_ST2  = O_STS + 16384;       // st^2
static constexpr size_t O_WNI  = O_ST2 + 16384;       // 512 f32 (padded)
static constexpr size_t O_DM   = O_WNI + 2048;        // 8*512 f32 demod
static constexpr size_t O_ACC  = O_DM + 16384;        // loss accumulators

static constexpr size_t OUT_CO = 16777216;            // d_out offset of co_out
static constexpr size_t OUT_L  = 17039360;            // d_out offset of losses

// parity-class tables for the transposed conv (gather form, wf[k]=W[2-k] folded)
__device__ const int c_ntap[4] = {4,2,2,1};
__device__ const int c_tap0[4] = {0,4,6,8};
__device__ const int c_ylim[4] = {33,33,32,32};
__device__ const int c_xlim[4] = {33,32,33,32};
__device__ const int c_py[4]  = {0,0,1,1};
__device__ const int c_px[4]  = {0,1,0,1};
__device__ const int c_dy[9] = {-1,-1,0,0, -1,0, 0,0, 0};
__device__ const int c_dx[9] = {-1,0,-1,0, 0,0, -1,0, 0};
__device__ const int c_ky[9] = {2,2,0,0, 2,0, 1,1, 1};
__device__ const int c_kx[9] = {2,0,2,0, 1,1, 2,0, 1};

__device__ __forceinline__ float wave_red(float v) {
#pragma unroll
  for (int s = 32; s > 0; s >>= 1) v += __shfl_down(v, s);
  return v;
}

// ---------------- small kernels ----------------

// cl softmax, grouped (round(softmax(500*cl))+1e-6), style_base
__global__ __launch_bounds__(512) void k_prep(const float* __restrict__ cluster,
    const float* __restrict__ tmpr, const float* __restrict__ style,
    const float* __restrict__ mb_w, const float* __restrict__ mb_b,
    float* __restrict__ cl, float* __restrict__ gr, float* __restrict__ sb) {
  int c = threadIdx.x;
  float t = 5.f / (1.f + expf(-tmpr[0]));
  float v[16];
  float m = -1e30f;
#pragma unroll
  for (int g = 0; g < 16; g++) { v[g] = t * cluster[g*512 + c]; m = fmaxf(m, v[g]); }
  float s = 0.f;
#pragma unroll
  for (int g = 0; g < 16; g++) { v[g] = expf(v[g] - m); s += v[g]; }
  float inv = 1.f / s;
  float clv[16];
  float m2 = -1e30f;
#pragma unroll
  for (int g = 0; g < 16; g++) { clv[g] = v[g]*inv; cl[g*512 + c] = clv[g]; m2 = fmaxf(m2, 500.f*clv[g]); }
  float s2 = 0.f; float e2[16];
#pragma unroll
  for (int g = 0; g < 16; g++) { e2[g] = expf(500.f*clv[g] - m2); s2 += e2[g]; }
  float i2 = 1.f / s2;
#pragma unroll
  for (int g = 0; g < 16; g++) gr[g*512 + c] = rintf(e2[g]*i2) + 1e-6f;
  if (c < 128) {
    int b = c >> 4, g = c & 15;
    const float* s1 = style + b*1024;
    const float* mw = mb_w + g*512;
    float acc = 0.f;
    for (int d = 0; d < 512; d++) acc = fmaf(s1[d], mw[d], acc);
    sb[b*16 + g] = acc*LIN_SCALE + mb_b[g];
  }
}

// st0[b,c] = lin_scale * <s2[b,:], mod_w[c,:]> + mod_b[c]
__global__ __launch_bounds__(512) void k_st0(const float* __restrict__ style,
    const float* __restrict__ mod_w, const float* __restrict__ mod_b, float* __restrict__ st0) {
  int b = blockIdx.x, c = threadIdx.x;
  __shared__ float s2s[512];
  s2s[c] = style[b*1024 + 512 + c];
  __syncthreads();
  const float* mw = mod_w + (size_t)c*512;
  float acc = 0.f;
  for (int d = 0; d < 512; d++) acc = fmaf(s2s[d], mw[d], acc);
  st0[b*512 + c] = acc*LIN_SCALE + mod_b[c];
}

// group-norm style mixing -> sts (st*scale), st2 (st^2)
__global__ __launch_bounds__(512) void k_stylemix(const float* __restrict__ st0,
    const float* __restrict__ gr, const float* __restrict__ sb,
    float* __restrict__ sts, float* __restrict__ st2) {
  int b = blockIdx.x, c = threadIdx.x;
  float s = st0[b*512 + c];
  float grv[16];
#pragma unroll
  for (int g = 0; g < 16; g++) grv[g] = gr[g*512 + c];
  __shared__ float red[16][8];
  __shared__ float inv[16];
  __shared__ float sbb[16];
  int wav = c >> 6, lane = c & 63;
#pragma unroll
  for (int g = 0; g < 16; g++) {
    float v = grv[g]*s; v *= v;
    v = wave_red(v);
    if (lane == 0) red[g][wav] = v;
  }
  if (c < 16) sbb[c] = sb[b*16 + c];
  __syncthreads();
  if (c < 16) {
    float tt = 0.f;
#pragma unroll
    for (int w = 0; w < 8; w++) tt += red[c][w];
    inv[c] = 1.f / fmaxf(sqrtf(tt), 1e-12f);
  }
  __syncthreads();
  float f = 0.f;
#pragma unroll
  for (int g = 0; g < 16; g++) f += grv[g]*inv[g]*sbb[g];
  float sn = s*f;
  sts[b*512 + c] = sn*SCALE;
  st2[b*512 + c] = sn*sn;
}

// Wsq[o,i] = sum_kk W^2 ; wni[o] = 1/max(||Wflat[o]||,1e-12)
__global__ __launch_bounds__(512) void k_wsq(const float* __restrict__ W,
    float* __restrict__ wsq, float* __restrict__ wni) {
  int o = blockIdx.x, i = threadIdx.x;
  const float* wp = W + ((size_t)o*512 + i)*9;
  float s = 0.f;
#pragma unroll
  for (int k = 0; k < 9; k++) s = fmaf(wp[k], wp[k], s);
  wsq[o*512 + i] = s;
  float t = wave_red(s);
  __shared__ float r8[8];
  if ((i & 63) == 0) r8[i >> 6] = t;
  __syncthreads();
  if (i == 0) {
    float tt = 0.f;
#pragma unroll
    for (int w = 0; w < 8; w++) tt += r8[w];
    wni[o] = 1.f / fmaxf(sqrtf(tt), 1e-12f);
  }
}

__global__ __launch_bounds__(512) void k_demod(const float* __restrict__ st2,
    const float* __restrict__ wsq, float* __restrict__ dm) {
  int b = blockIdx.x, o = threadIdx.x;
  __shared__ float s2s[512];
  s2s[o] = st2[b*512 + o];
  __syncthreads();
  const float* wp = wsq + (size_t)o*512;
  float acc = 0.f;
  for (int i = 0; i < 512; i++) acc = fmaf(s2s[i], wp[i], acc);
  dm[b*512 + o] = rsqrtf((1.0f/4608.0f)*acc + 1e-8f);
}

__global__ __launch_bounds__(256) void k_losses(const float* __restrict__ co,
    const float* __restrict__ cl, const float* __restrict__ gate, float* __restrict__ accs) {
  int i = blockIdx.x;
  float gg = 1.f / (1.f + expf(-gate[0]));
  float cli[16];
#pragma unroll
  for (int k = 0; k < 16; k++) cli[k] = cl[k*512 + i];
  float p1 = 0.f, p2 = 0.f;
  for (int j = threadIdx.x; j < 512; j += 256) {
    float d = 0.f;
#pragma unroll
    for (int k = 0; k < 16; k++) d = fmaf(cli[k], cl[k*512 + j], d);
    float S = 1.f / (1.f + expf(-50.f*(co[i*512 + j] - gg)));
    float e = d - S;
    p1 = fmaf(e, e, p1); p2 += S;
  }
  p1 = wave_red(p1); p2 = wave_red(p2);
  if ((threadIdx.x & 63) == 0) { atomicAdd(&accs[0], p1); atomicAdd(&accs[1], p2); }
}

__global__ void k_fin(const float* __restrict__ accs, float* __restrict__ out_tail) {
  float d = 16384.f - accs[1];
  out_tail[0] = accs[0];
  out_tail[1] = d*d;
}

// Wr[t][i][o] = W[o][i][ky_t][kx_t]  (coalesced writes along o)
__global__ __launch_bounds__(512) void k_wreorg(const float* __restrict__ W, float* __restrict__ wr) {
  int t = blockIdx.x, i = blockIdx.y, o = threadIdx.x;
  wr[((size_t)t*512 + i)*512 + o] = W[(size_t)o*4608 + i*9 + c_ky[t]*3 + c_kx[t]];
}

// xs[b][y+1][x+1][i] = x[b][i][y][x] * sts[b][i]   (NHWC, zero ring from memset)
__global__ __launch_bounds__(256) void k_xsprep(const float* __restrict__ x,
    const float* __restrict__ sts, float* __restrict__ xs) {
  int b = blockIdx.x;
  int p0 = blockIdx.y * 64;
  int i0 = blockIdx.z * 64;
  __shared__ float L[64][65];
  int tid = threadIdx.x;
  int lp = tid & 63, li = tid >> 6;
  const float* xp = x + ((size_t)b*512 + i0)*1024 + p0;
#pragma unroll
  for (int ii = 0; ii < 16; ii++) {
    int i = li + 4*ii;
    L[i][lp] = xp[(size_t)i*1024 + lp];
  }
  __syncthreads();
  int iw = tid & 63, pw = tid >> 6;
  float sv = sts[b*512 + i0 + iw];
#pragma unroll
  for (int pp = 0; pp < 16; pp++) {
    int pix = p0 + pw + 4*pp;
    int y = pix >> 5, xq = pix & 31;
    xs[(((size_t)b*34 + (y+1))*34 + (xq+1))*512 + i0 + iw] = L[iw][pw + 4*pp] * sv;
  }
}

// transposed conv as 4 parity-class GEMMs: C[r,o], r=(b,y,x); A=xs patches (K-contig), B=Wr
__global__ __launch_bounds__(256) void k_convgemm(const float* __restrict__ xs,
    const float* __restrict__ wr, __hip_bfloat16* __restrict__ out1) {
  const int cls = blockIdx.z;
  const int ylim = c_ylim[cls], xlim = c_xlim[cls];
  const int M = NB * ylim * xlim;
  const int m0 = blockIdx.x * 64;
  if (m0 >= M) return;
  const int K = c_ntap[cls] * 512;
  const int t0 = c_tap0[cls];
  const int n0t = blockIdx.y * 64;

  __shared__ float As[16][64];
  __shared__ float Bs[16][64];

  const int tid = threadIdx.x;
  const int am = tid & 63, akc = tid >> 6;
  int r = m0 + am;
  const bool valid = r < M;
  int rr = valid ? r : 0;
  int b = rr / (ylim*xlim); int rem = rr - b*(ylim*xlim);
  int yy = rem / xlim; int xx = rem - yy*xlim;
  const float* apix = xs + (((size_t)b*34 + (yy+1))*34 + (xx+1))*512 + 4*akc;

  const int bkk = tid >> 4, bn0 = (tid & 15)*4;
  const float* bptr = wr + ((size_t)t0*512)*512 + n0t + bn0;

  float acc[4][4] = {{0.f,0.f,0.f,0.f},{0.f,0.f,0.f,0.f},{0.f,0.f,0.f,0.f},{0.f,0.f,0.f,0.f}};
  const int mr = (tid >> 4)*4, nc = (tid & 15)*4;

  for (int k0 = 0; k0 < K; k0 += 16) {
    int tap = t0 + (k0 >> 9);
    int doff = (c_dy[tap]*34 + c_dx[tap])*512 + (k0 & 511);
    float4 av;
    if (valid) av = *(const float4*)(apix + doff);
    else av = make_float4(0.f,0.f,0.f,0.f);
    As[4*akc+0][am] = av.x; As[4*akc+1][am] = av.y;
    As[4*akc+2][am] = av.z; As[4*akc+3][am] = av.w;
    float4 bv = *(const float4*)(bptr + (size_t)(k0 + bkk)*512);
    *((float4*)&Bs[bkk][bn0]) = bv;
    __syncthreads();
#pragma unroll
    for (int kk = 0; kk < 16; kk++) {
      float4 a4 = *(const float4*)&As[kk][mr];
      float4 b4 = *(const float4*)&Bs[kk][nc];
      float aa[4] = {a4.x,a4.y,a4.z,a4.w};
      float bb[4] = {b4.x,b4.y,b4.z,b4.w};
#pragma unroll
      for (int i2 = 0; i2 < 4; i2++)
#pragma unroll
        for (int j2 = 0; j2 < 4; j2++)
          acc[i2][j2] = fmaf(aa[i2], bb[j2], acc[i2][j2]);
    }
    __syncthreads();
  }
  const int py = c_py[cls], px = c_px[cls];
  for (int i2 = 0; i2 < 4; i2++) {
    int r2 = m0 + mr + i2;
    if (r2 >= M) break;
    int b2 = r2 / (ylim*xlim); int rem2 = r2 - b2*(ylim*xlim);
    int y2 = rem2 / xlim; int x2 = rem2 - y2*xlim;
    int p = 2*y2 + py, q = 2*x2 + px;
    __hip_bfloat16* dst = out1 + ((size_t)b2*512 + n0t + nc)*4225 + p*65 + q;
#pragma unroll
    for (int j2 = 0; j2 < 4; j2++)
      dst[(size_t)j2*4225] = __float2bfloat16(acc[i2][j2]);
  }
}

// co_out = wn @ wn.T via split-K (z=4) atomics
__global__ __launch_bounds__(256) void k_gram(const float* __restrict__ W,
    const float* __restrict__ wni, float* __restrict__ co_out) {
  const int m0 = blockIdx.x * 64, n0 = blockIdx.y * 64;
  const int kb = blockIdx.z * 1152;
  __shared__ float As[16][64];
  __shared__ float Bs[16][64];
  const int tid = threadIdx.x;
  const int am = tid & 63, akc = tid >> 6;
  const float* arow = W + (size_t)(m0 + am)*4608 + 4*akc;
  const float* brow = W + (size_t)(n0 + am)*4608 + 4*akc;
  float acc[4][4] = {{0.f,0.f,0.f,0.f},{0.f,0.f,0.f,0.f},{0.f,0.f,0.f,0.f},{0.f,0.f,0.f,0.f}};
  const int mr = (tid >> 4)*4, nc = (tid & 15)*4;
  for (int k0 = kb; k0 < kb + 1152; k0 += 16) {
    float4 av = *(const float4*)(arow + k0);
    float4 bv = *(const float4*)(brow + k0);
    As[4*akc+0][am] = av.x; As[4*akc+1][am] = av.y;
    As[4*akc+2][am] = av.z; As[4*akc+3][am] = av.w;
    Bs[4*akc+0][am] = bv.x; Bs[4*akc+1][am] = bv.y;
    Bs[4*akc+2][am] = bv.z; Bs[4*akc+3][am] = bv.w;
    __syncthreads();
#pragma unroll
    for (int kk = 0; kk < 16; kk++) {
      float4 a4 = *(const float4*)&As[kk][mr];
      float4 b4 = *(const float4*)&Bs[kk][nc];
      float aa[4] = {a4.x,a4.y,a4.z,a4.w};
      float bb[4] = {b4.x,b4.y,b4.z,b4.w};
#pragma unroll
      for (int i2 = 0; i2 < 4; i2++)
#pragma unroll
        for (int j2 = 0; j2 < 4; j2++)
          acc[i2][j2] = fmaf(aa[i2], bb[j2], acc[i2][j2]);
    }
    __syncthreads();
  }
  float wm[4], wn[4];
#pragma unroll
  for (int i2 = 0; i2 < 4; i2++) { wm[i2] = wni[m0+mr+i2]; wn[i2] = wni[n0+nc+i2]; }
#pragma unroll
  for (int i2 = 0; i2 < 4; i2++)
#pragma unroll
    for (int j2 = 0; j2 < 4; j2++)
      atomicAdd(&co_out[(size_t)(m0+mr+i2)*512 + n0+nc+j2], acc[i2][j2]*wm[i2]*wn[j2]);
}

// 4x4 blur (separable [1,3,3,1]/4) + demod + noise + bias + leaky*sqrt2
__global__ __launch_bounds__(256) void k_blur(const __hip_bfloat16* __restrict__ out1,
    const float* __restrict__ dm, const float* __restrict__ noise,
    const float* __restrict__ nw, const float* __restrict__ fb, float* __restrict__ out) {
  int bo = blockIdx.x;
  int b = bo >> 9, o = bo & 511;
  const __hip_bfloat16* pl = out1 + (size_t)bo*4225;
  float dmv = dm[bo];
  float nwv = nw[0];
  float bv = fb[o];
  int Q = threadIdx.x & 63;
  int qy = threadIdx.x >> 6;
  float hs[18];
#pragma unroll
  for (int rm = 0; rm < 18; rm++) {
    int m = 16*qy - 1 + rm;
    float s = 0.f;
    if (m >= 0 && m <= 64) {
      const __hip_bfloat16* row = pl + m*65;
      float v0 = (Q >= 1)  ? __bfloat162float(row[Q-1]) : 0.f;
      float v1 = __bfloat162float(row[Q]);
      float v2 = __bfloat162float(row[Q+1]);
      float v3 = (Q <= 62) ? __bfloat162float(row[Q+2]) : 0.f;
      s = 0.25f*v0 + 0.75f*v1 + 0.75f*v2 + 0.25f*v3;
    }
    hs[rm] = s;
  }
  float* op = out + ((size_t)bo << 12);
  const float* npl = noise + ((size_t)b << 12);
#pragma unroll
  for (int pp = 0; pp < 16; pp++) {
    int P = 16*qy + pp;
    float s = 0.25f*hs[pp] + 0.75f*hs[pp+1] + 0.75f*hs[pp+2] + 0.25f*hs[pp+3];
    float v = fmaf(dmv, s, fmaf(nwv, npl[P*64 + Q], bv));
    v = (v >= 0.f ? v : 0.2f*v) * 1.4142135623730951f;
    op[P*64 + Q] = v;
  }
}

extern "C" void kernel_launch(void* const* d_in, const int* in_sizes, int n_in,
                              void* d_out, int out_size, void* d_ws, size_t ws_size,
                              hipStream_t stream) {
  const float* x       = (const float*)d_in[0];
  const float* co      = (const float*)d_in[1];
  const float* style   = (const float*)d_in[2];
  const float* noise   = (const float*)d_in[3];
  const float* W       = (const float*)d_in[4];
  const float* mb_w    = (const float*)d_in[5];
  const float* mb_b    = (const float*)d_in[6];
  const float* mod_w   = (const float*)d_in[7];
  const float* mod_b   = (const float*)d_in[8];
  const float* cluster = (const float*)d_in[9];
  const float* gate    = (const float*)d_in[10];
  const float* tmpr    = (const float*)d_in[11];
  const float* nw      = (const float*)d_in[12];
  const float* fb      = (const float*)d_in[13];
  float* out = (float*)d_out;
  char* ws = (char*)d_ws;

  float* xs  = (float*)(ws + O_XS);
  __hip_bfloat16* out1 = (__hip_bfloat16*)(ws + O_OUT1);
  float* wr  = (float*)(ws + O_WR);
  float* wsq = (float*)(ws + O_WSQ);
  float* cl  = (float*)(ws + O_CL);
  float* gr  = (float*)(ws + O_GR);
  float* sb  = (float*)(ws + O_SB);
  float* st0 = (float*)(ws + O_ST0);
  float* sts = (float*)(ws + O_STS);
  float* st2 = (float*)(ws + O_ST2);
  float* wni = (float*)(ws + O_WNI);
  float* dm  = (float*)(ws + O_DM);
  float* accs = (float*)(ws + O_ACC);

  hipMemsetAsync(xs, 0, 18939904, stream);
  hipMemsetAsync(accs, 0, 256, stream);
  hipMemsetAsync(out + OUT_CO, 0, 262144*sizeof(float), stream);

  k_prep<<<1, 512, 0, stream>>>(cluster, tmpr, style, mb_w, mb_b, cl, gr, sb);
  k_st0<<<NB, 512, 0, stream>>>(style, mod_w, mod_b, st0);
  k_stylemix<<<NB, 512, 0, stream>>>(st0, gr, sb, sts, st2);
  k_wsq<<<512, 512, 0, stream>>>(W, wsq, wni);
  k_demod<<<NB, 512, 0, stream>>>(st2, wsq, dm);
  k_losses<<<512, 256, 0, stream>>>(co, cl, gate, accs);
  k_fin<<<1, 1, 0, stream>>>(accs, out + OUT_L);
  k_wreorg<<<dim3(9, 512), 512, 0, stream>>>(W, wr);
  k_xsprep<<<dim3(NB, 16, 8), 256, 0, stream>>>(x, sts, xs);
  k_convgemm<<<dim3(137, 8, 4), 256, 0, stream>>>(xs, wr, out1);
  k_gram<<<dim3(8, 8, 4), 256, 0, stream>>>(W, wni, out + OUT_CO);
  k_blur<<<4096, 256, 0, stream>>>(out1, dm, noise, nw, fb, out);
}

// Round 2
// 388.759 us; speedup vs baseline: 2.3083x; 2.3083x over previous
//
#include <hip/hip_runtime.h>
#include <hip/hip_bf16.h>

#define NB 8
#define LIN_SCALE 0.044194173824159216f
#define SCALE 0.014731391274719736f

typedef __attribute__((ext_vector_type(8))) short short8;
typedef __attribute__((ext_vector_type(4))) float floatx4;

// ---------------- workspace layout (bytes) ----------------
static constexpr size_t O_XS   = 0;                   // 8*34*34*512 bf16 = 9,469,952 (zero-padded NHWC modulated x)
static constexpr size_t O_OUT1 = 9469952;             // parity planes bf16: 34,611,200
static constexpr size_t O_WRT  = 44081152;            // 9*512*512 bf16 = 4,718,592  wrt[tap][o][i]
static constexpr size_t O_WB   = 48799744;            // 512*4608 bf16 = 4,718,592   wb[o][k]
static constexpr size_t O_PG   = 53518336;            // 8*512*512 f32 = 8,388,608   gram partials
static constexpr size_t O_WSQ  = 61906944;            // 512*512 f32
static constexpr size_t O_CL   = 62955520;            // 16*512 f32
static constexpr size_t O_GR   = O_CL + 32768;
static constexpr size_t O_SB   = O_GR + 32768;
static constexpr size_t O_ST0  = O_SB + 1024;
static constexpr size_t O_STS  = O_ST0 + 16384;
static constexpr size_t O_ST2  = O_STS + 16384;
static constexpr size_t O_WNI  = O_ST2 + 16384;
static constexpr size_t O_DM   = O_WNI + 2048;
static constexpr size_t O_ACC  = O_DM + 16384;

static constexpr size_t OUT_CO = 16777216;            // d_out offset of co_out
static constexpr size_t OUT_L  = 17039360;            // d_out offset of losses

// parity-class tables for the transposed conv (gather form, wf[k]=W[2-k] folded)
__device__ const int c_ylim[4] = {33,33,32,32};
__device__ const int c_xlim[4] = {33,32,33,32};
__device__ const int c_ntap[4] = {4,2,2,1};
__device__ const int c_tap0[4] = {0,4,6,8};
__device__ const int c_dy[9] = {-1,-1,0,0, -1,0, 0,0, 0};
__device__ const int c_dx[9] = {-1,0,-1,0, 0,0, -1,0, 0};
__device__ const int c_ky[9] = {2,2,0,0, 2,0, 1,1, 1};
__device__ const int c_kx[9] = {2,0,2,0, 1,1, 2,0, 1};
// plane element offsets / per-class M=8*npix
__device__ const long c_poff[4] = {0, 4460544, 8785920, 13111296};

__device__ __forceinline__ float wave_red(float v) {
#pragma unroll
  for (int s = 32; s > 0; s >>= 1) v += __shfl_down(v, s);
  return v;
}

__device__ __forceinline__ void gl_lds16(const void* g, void* l) {
  __builtin_amdgcn_global_load_lds((const __attribute__((address_space(1))) void*)g,
                                   (__attribute__((address_space(3))) void*)l, 16, 0, 0);
}

__device__ __forceinline__ unsigned short bf16b(float f) {
  union { __hip_bfloat16 h; unsigned short u; } cv;
  cv.h = __float2bfloat16(f);
  return cv.u;
}

// ---------------- small kernels (unchanged from round 1) ----------------

__global__ __launch_bounds__(512) void k_prep(const float* __restrict__ cluster,
    const float* __restrict__ tmpr, const float* __restrict__ style,
    const float* __restrict__ mb_w, const float* __restrict__ mb_b,
    float* __restrict__ cl, float* __restrict__ gr, float* __restrict__ sb) {
  int c = threadIdx.x;
  float t = 5.f / (1.f + expf(-tmpr[0]));
  float v[16];
  float m = -1e30f;
#pragma unroll
  for (int g = 0; g < 16; g++) { v[g] = t * cluster[g*512 + c]; m = fmaxf(m, v[g]); }
  float s = 0.f;
#pragma unroll
  for (int g = 0; g < 16; g++) { v[g] = expf(v[g] - m); s += v[g]; }
  float inv = 1.f / s;
  float clv[16];
  float m2 = -1e30f;
#pragma unroll
  for (int g = 0; g < 16; g++) { clv[g] = v[g]*inv; cl[g*512 + c] = clv[g]; m2 = fmaxf(m2, 500.f*clv[g]); }
  float s2 = 0.f; float e2[16];
#pragma unroll
  for (int g = 0; g < 16; g++) { e2[g] = expf(500.f*clv[g] - m2); s2 += e2[g]; }
  float i2 = 1.f / s2;
#pragma unroll
  for (int g = 0; g < 16; g++) gr[g*512 + c] = rintf(e2[g]*i2) + 1e-6f;
  if (c < 128) {
    int b = c >> 4, g = c & 15;
    const float* s1 = style + b*1024;
    const float* mw = mb_w + g*512;
    float acc = 0.f;
    for (int d = 0; d < 512; d++) acc = fmaf(s1[d], mw[d], acc);
    sb[b*16 + g] = acc*LIN_SCALE + mb_b[g];
  }
}

__global__ __launch_bounds__(512) void k_st0(const float* __restrict__ style,
    const float* __restrict__ mod_w, const float* __restrict__ mod_b, float* __restrict__ st0) {
  int b = blockIdx.x, c = threadIdx.x;
  __shared__ float s2s[512];
  s2s[c] = style[b*1024 + 512 + c];
  __syncthreads();
  const float* mw = mod_w + (size_t)c*512;
  float acc = 0.f;
  for (int d = 0; d < 512; d++) acc = fmaf(s2s[d], mw[d], acc);
  st0[b*512 + c] = acc*LIN_SCALE + mod_b[c];
}

__global__ __launch_bounds__(512) void k_stylemix(const float* __restrict__ st0,
    const float* __restrict__ gr, const float* __restrict__ sb,
    float* __restrict__ sts, float* __restrict__ st2) {
  int b = blockIdx.x, c = threadIdx.x;
  float s = st0[b*512 + c];
  float grv[16];
#pragma unroll
  for (int g = 0; g < 16; g++) grv[g] = gr[g*512 + c];
  __shared__ float red[16][8];
  __shared__ float inv[16];
  __shared__ float sbb[16];
  int wav = c >> 6, lane = c & 63;
#pragma unroll
  for (int g = 0; g < 16; g++) {
    float v = grv[g]*s; v *= v;
    v = wave_red(v);
    if (lane == 0) red[g][wav] = v;
  }
  if (c < 16) sbb[c] = sb[b*16 + c];
  __syncthreads();
  if (c < 16) {
    float tt = 0.f;
#pragma unroll
    for (int w = 0; w < 8; w++) tt += red[c][w];
    inv[c] = 1.f / fmaxf(sqrtf(tt), 1e-12f);
  }
  __syncthreads();
  float f = 0.f;
#pragma unroll
  for (int g = 0; g < 16; g++) f += grv[g]*inv[g]*sbb[g];
  float sn = s*f;
  sts[b*512 + c] = sn*SCALE;
  st2[b*512 + c] = sn*sn;
}

__global__ __launch_bounds__(512) void k_wsq(const float* __restrict__ W,
    float* __restrict__ wsq, float* __restrict__ wni) {
  int o = blockIdx.x, i = threadIdx.x;
  const float* wp = W + ((size_t)o*512 + i)*9;
  float s = 0.f;
#pragma unroll
  for (int k = 0; k < 9; k++) s = fmaf(wp[k], wp[k], s);
  wsq[o*512 + i] = s;
  float t = wave_red(s);
  __shared__ float r8[8];
  if ((i & 63) == 0) r8[i >> 6] = t;
  __syncthreads();
  if (i == 0) {
    float tt = 0.f;
#pragma unroll
    for (int w = 0; w < 8; w++) tt += r8[w];
    wni[o] = 1.f / fmaxf(sqrtf(tt), 1e-12f);
  }
}

__global__ __launch_bounds__(512) void k_demod(const float* __restrict__ st2,
    const float* __restrict__ wsq, float* __restrict__ dm) {
  int b = blockIdx.x, o = threadIdx.x;
  __shared__ float s2s[512];
  s2s[o] = st2[b*512 + o];
  __syncthreads();
  const float* wp = wsq + (size_t)o*512;
  float acc = 0.f;
  for (int i = 0; i < 512; i++) acc = fmaf(s2s[i], wp[i], acc);
  dm[b*512 + o] = rsqrtf((1.0f/4608.0f)*acc + 1e-8f);
}

__global__ __launch_bounds__(256) void k_losses(const float* __restrict__ co,
    const float* __restrict__ cl, const float* __restrict__ gate, float* __restrict__ accs) {
  int i = blockIdx.x;
  float gg = 1.f / (1.f + expf(-gate[0]));
  float cli[16];
#pragma unroll
  for (int k = 0; k < 16; k++) cli[k] = cl[k*512 + i];
  float p1 = 0.f, p2 = 0.f;
  for (int j = threadIdx.x; j < 512; j += 256) {
    float d = 0.f;
#pragma unroll
    for (int k = 0; k < 16; k++) d = fmaf(cli[k], cl[k*512 + j], d);
    float S = 1.f / (1.f + expf(-50.f*(co[i*512 + j] - gg)));
    float e = d - S;
    p1 = fmaf(e, e, p1); p2 += S;
  }
  p1 = wave_red(p1); p2 = wave_red(p2);
  if ((threadIdx.x & 63) == 0) { atomicAdd(&accs[0], p1); atomicAdd(&accs[1], p2); }
}

__global__ void k_fin(const float* __restrict__ accs, float* __restrict__ out_tail) {
  float d = 16384.f - accs[1];
  out_tail[0] = accs[0];
  out_tail[1] = d*d;
}

// ---------------- bf16 prep kernels ----------------

// wrt[t][o][i] = bf16(W[o][i][ky_t][kx_t])
__global__ __launch_bounds__(512) void k_wreorg(const float* __restrict__ W, __hip_bfloat16* __restrict__ wrt) {
  const int o = blockIdx.x;
  __shared__ float wrow[4608];
  for (int i = threadIdx.x; i < 4608; i += 512) wrow[i] = W[(size_t)o*4608 + i];
  __syncthreads();
  const int i = threadIdx.x;
#pragma unroll
  for (int t = 0; t < 9; t++) {
    const int km = c_ky[t]*3 + c_kx[t];
    wrt[((size_t)t*512 + o)*512 + i] = __float2bfloat16(wrow[i*9 + km]);
  }
}

// wb = bf16(W) flat
__global__ __launch_bounds__(256) void k_wbf(const float* __restrict__ W, unsigned short* __restrict__ wb) {
  const int i = blockIdx.x*256 + threadIdx.x;  // 589824 float4s
  const float4 v = ((const float4*)W)[i];
  ushort4 u;
  u.x = bf16b(v.x); u.y = bf16b(v.y); u.z = bf16b(v.z); u.w = bf16b(v.w);
  ((ushort4*)wb)[i] = u;
}

// xs[b][y+1][x+1][i] = bf16(x[b][i][y][x] * sts[b][i])  (NHWC, zero ring from memset)
__global__ __launch_bounds__(256) void k_xsprep(const float* __restrict__ x,
    const float* __restrict__ sts, __hip_bfloat16* __restrict__ xs) {
  int b = blockIdx.x;
  int p0 = blockIdx.y * 64;
  int i0 = blockIdx.z * 64;
  __shared__ float L[64][65];
  int tid = threadIdx.x;
  int lp = tid & 63, li = tid >> 6;
  const float* xp = x + ((size_t)b*512 + i0)*1024 + p0;
#pragma unroll
  for (int ii = 0; ii < 16; ii++) {
    int i = li + 4*ii;
    L[i][lp] = xp[(size_t)i*1024 + lp];
  }
  __syncthreads();
  int iw = tid & 63, pw = tid >> 6;
  float sv = sts[b*512 + i0 + iw];
#pragma unroll
  for (int pp = 0; pp < 16; pp++) {
    int pix = p0 + pw + 4*pp;
    int y = pix >> 5, xq = pix & 31;
    xs[(((size_t)b*34 + (y+1))*34 + (xq+1))*512 + i0 + iw] = __float2bfloat16(L[iw][pw + 4*pp] * sv);
  }
}

// ---------------- MFMA transposed-conv GEMM ----------------
// C[r, o], r=(b,y,x) per parity class; A=xs patches [m][k], B=wrt [n][k] (B^T layout)
// out1 parity planes: plane[cls] + o*M + r  (m-contiguous for coalesced stores)
__global__ __launch_bounds__(256, 2) void k_convmfma(
    const __hip_bfloat16* __restrict__ xs, const __hip_bfloat16* __restrict__ wrt,
    __hip_bfloat16* __restrict__ out1) {
  const int cls = blockIdx.z;
  const int xlim = c_xlim[cls];
  const int npix = c_ylim[cls] * xlim;
  const int M = NB * npix;
  const int m0 = blockIdx.x * 128;
  if (m0 >= M) return;
  const int n0 = blockIdx.y * 128;
  const int t0 = c_tap0[cls];
  const int ntap = c_ntap[cls];

  __shared__ __hip_bfloat16 smem[17408];  // A[128][32] @0, B[128][32] @4096; epilogue Ct[128][136]

  const int tid = threadIdx.x;
  long abase[2]; long bbase[2]; int ldso[2];
#pragma unroll
  for (int r = 0; r < 2; r++) {
    const int idx = r * 256 + tid;
    const int row = idx >> 2, kc = (idx & 3) << 3;
    int rm = m0 + row; if (rm >= M) rm = 0;
    const int b = rm / npix; const int rem = rm - b * npix;
    const int yy = rem / xlim; const int xx = rem - yy * xlim;
    abase[r] = ((long)(b * 34 + yy + 1) * 34 + (xx + 1)) * 512 + kc;
    bbase[r] = ((long)(t0 * 512 + n0 + row)) * 512 + kc;
    ldso[r] = idx << 3;
  }

  const int lane = tid & 63;
  const int wv = tid >> 6;
  const int wm = (wv >> 1) << 6, wn = (wv & 1) << 6;
  const int col16 = lane & 15, quad = lane >> 4;

  int aoff[4], boff[4];
#pragma unroll
  for (int t = 0; t < 4; t++) {
    aoff[t] = (wm + t * 16 + col16) * 32 + quad * 8;
    boff[t] = 4096 + (wn + t * 16 + col16) * 32 + quad * 8;
  }

  floatx4 acc[4][4];
#pragma unroll
  for (int i = 0; i < 4; i++)
#pragma unroll
    for (int j = 0; j < 4; j++) acc[i][j] = (floatx4){0.f, 0.f, 0.f, 0.f};

  for (int tp = 0; tp < ntap; tp++) {
    const int tap = t0 + tp;
    const long adel = (long)((c_dy[tap] * 34 + c_dx[tap]) * 512);
    const long bdel = (long)tp << 18;
    for (int ks = 0; ks < 16; ks++) {
      const int kk = ks << 5;
#pragma unroll
      for (int r = 0; r < 2; r++) {
        gl_lds16(xs + (abase[r] + adel + kk), smem + ldso[r]);
        gl_lds16(wrt + (bbase[r] + bdel + kk), smem + 4096 + ldso[r]);
      }
      __syncthreads();
      short8 af[4], bf[4];
#pragma unroll
      for (int t = 0; t < 4; t++) {
        af[t] = *(const short8*)(smem + aoff[t]);
        bf[t] = *(const short8*)(smem + boff[t]);
      }
#pragma unroll
      for (int i = 0; i < 4; i++)
#pragma unroll
        for (int j = 0; j < 4; j++)
          acc[i][j] = __builtin_amdgcn_mfma_f32_16x16x32_bf16(af[i], bf[j], acc[i][j], 0, 0, 0);
      __syncthreads();
    }
  }

  // transpose C through LDS: Ct[n][136] (pad 8 keeps 16B-aligned rows, 2-way-free banks)
#pragma unroll
  for (int i = 0; i < 4; i++) {
    const int mrow = wm + i * 16 + (quad << 2);
#pragma unroll
    for (int j = 0; j < 4; j++) {
      const int ncol = wn + j * 16 + col16;
#pragma unroll
      for (int r = 0; r < 4; r++)
        smem[ncol * 136 + mrow + r] = __float2bfloat16(acc[i][j][r]);
    }
  }
  __syncthreads();

  __hip_bfloat16* plane = out1 + c_poff[cls];
#pragma unroll
  for (int it = 0; it < 8; it++) {
    const int c = it * 256 + tid;
    const int o = c >> 4, ml = (c & 15) << 3;
    const int mg = m0 + ml;
    if (mg < M) {
      const ushort4 v = *(const ushort4*)(smem + o * 136 + ml);
      *(ushort4*)(plane + (long)(n0 + o) * M + mg) = v;
    }
  }
}

// ---------------- gram via MFMA, split-K=8 ----------------
__global__ __launch_bounds__(256, 2) void k_gram(const __hip_bfloat16* __restrict__ wb,
                                                 float* __restrict__ pgram) {
  const int m0 = blockIdx.x * 128, n0 = blockIdx.y * 128;
  const long kz = (long)blockIdx.z * 576;
  __shared__ __hip_bfloat16 smem[8192];
  const int tid = threadIdx.x;
  long abase[2], bbase[2]; int ldso[2];
#pragma unroll
  for (int r = 0; r < 2; r++) {
    const int idx = r * 256 + tid;
    const int row = idx >> 2, kc = (idx & 3) << 3;
    abase[r] = (long)(m0 + row) * 4608 + kz + kc;
    bbase[r] = (long)(n0 + row) * 4608 + kz + kc;
    ldso[r] = idx << 3;
  }
  const int lane = tid & 63, wv = tid >> 6;
  const int wm = (wv >> 1) << 6, wn = (wv & 1) << 6;
  const int col16 = lane & 15, quad = lane >> 4;
  int aoff[4], boff[4];
#pragma unroll
  for (int t = 0; t < 4; t++) {
    aoff[t] = (wm + t * 16 + col16) * 32 + quad * 8;
    boff[t] = 4096 + (wn + t * 16 + col16) * 32 + quad * 8;
  }
  floatx4 acc[4][4];
#pragma unroll
  for (int i = 0; i < 4; i++)
#pragma unroll
    for (int j = 0; j < 4; j++) acc[i][j] = (floatx4){0.f, 0.f, 0.f, 0.f};
  for (int ks = 0; ks < 18; ks++) {
    const int kk = ks << 5;
#pragma unroll
    for (int r = 0; r < 2; r++) {
      gl_lds16(wb + (abase[r] + kk), smem + ldso[r]);
      gl_lds16(wb + (bbase[r] + kk), smem + 4096 + ldso[r]);
    }
    __syncthreads();
    short8 af[4], bf[4];
#pragma unroll
    for (int t = 0; t < 4; t++) {
      af[t] = *(const short8*)(smem + aoff[t]);
      bf[t] = *(const short8*)(smem + boff[t]);
    }
#pragma unroll
    for (int i = 0; i < 4; i++)
#pragma unroll
      for (int j = 0; j < 4; j++)
        acc[i][j] = __builtin_amdgcn_mfma_f32_16x16x32_bf16(af[i], bf[j], acc[i][j], 0, 0, 0);
    __syncthreads();
  }
  float* pg = pgram + (size_t)blockIdx.z * 262144;
#pragma unroll
  for (int i = 0; i < 4; i++)
#pragma unroll
    for (int j = 0; j < 4; j++) {
      const int m = m0 + wm + i * 16 + (quad << 2);
      const int n = n0 + wn + j * 16 + col16;
#pragma unroll
      for (int r = 0; r < 4; r++) pg[(size_t)(m + r) * 512 + n] = acc[i][j][r];
    }
}

__global__ __launch_bounds__(256) void k_gramred(const float* __restrict__ pgram,
    const float* __restrict__ wni, float* __restrict__ co_out) {
  const int idx = blockIdx.x * 256 + threadIdx.x;
  float s = 0.f;
#pragma unroll
  for (int z = 0; z < 8; z++) s += pgram[(size_t)z * 262144 + idx];
  const int m = idx >> 9, n = idx & 511;
  co_out[idx] = s * wni[m] * wni[n];
}

// ---------------- blur from parity planes + epilogue ----------------
__device__ __forceinline__ float ldq(const __hip_bfloat16* re, const __hip_bfloat16* ro, int q) {
  if (q < 0 || q > 64) return 0.f;
  return __bfloat162float((q & 1) ? ro[q >> 1] : re[q >> 1]);
}

__global__ __launch_bounds__(256) void k_blur(const __hip_bfloat16* __restrict__ out1,
    const float* __restrict__ dm, const float* __restrict__ noise,
    const float* __restrict__ nw, const float* __restrict__ fb, float* __restrict__ out) {
  const int bo = blockIdx.x;
  const int b = bo >> 9, o = bo & 511;
  const float dmv = dm[bo];
  const float nwv = nw[0];
  const float bv = fb[o];
  const __hip_bfloat16* rbE[2];
  const __hip_bfloat16* rbO[2];
  rbE[0] = out1 + 0        + (long)o * 8712 + b * 1089;  // cls0: m even, q even, xlim 33
  rbO[0] = out1 + 4460544  + (long)o * 8448 + b * 1056;  // cls1: m even, q odd,  xlim 32
  rbE[1] = out1 + 8785920  + (long)o * 8448 + b * 1056;  // cls2: m odd,  q even, xlim 33
  rbO[1] = out1 + 13111296 + (long)o * 8192 + b * 1024;  // cls3: m odd,  q odd,  xlim 32
  const int Q = threadIdx.x & 63;
  const int qy = threadIdx.x >> 6;
  const int mbase = 16 * qy - 1;
  float hs[18];
#pragma unroll
  for (int rm = 0; rm < 18; rm++) {
    const int m = mbase + rm;
    float s = 0.f;
    if (m >= 0 && m <= 64) {
      const int pm = (rm + 1) & 1;          // == m&1 (mbase is odd)
      const int y = m >> 1;
      const __hip_bfloat16* re = rbE[pm] + y * 33;
      const __hip_bfloat16* ro = rbO[pm] + y * 32;
      float v0 = ldq(re, ro, Q - 1);
      float v1 = ldq(re, ro, Q);
      float v2 = ldq(re, ro, Q + 1);
      float v3 = ldq(re, ro, Q + 2);
      s = 0.25f * (v0 + v3) + 0.75f * (v1 + v2);
    }
    hs[rm] = s;
  }
  float* op = out + ((size_t)bo << 12);
  const float* npl = noise + ((size_t)b << 12);
#pragma unroll
  for (int pp = 0; pp < 16; pp++) {
    const int P = 16 * qy + pp;
    float s = 0.25f * (hs[pp] + hs[pp + 3]) + 0.75f * (hs[pp + 1] + hs[pp + 2]);
    float v = fmaf(dmv, s, fmaf(nwv, npl[P * 64 + Q], bv));
    v = (v >= 0.f ? v : 0.2f * v) * 1.4142135623730951f;
    op[P * 64 + Q] = v;
  }
}

extern "C" void kernel_launch(void* const* d_in, const int* in_sizes, int n_in,
                              void* d_out, int out_size, void* d_ws, size_t ws_size,
                              hipStream_t stream) {
  const float* x       = (const float*)d_in[0];
  const float* co      = (const float*)d_in[1];
  const float* style   = (const float*)d_in[2];
  const float* noise   = (const float*)d_in[3];
  const float* W       = (const float*)d_in[4];
  const float* mb_w    = (const float*)d_in[5];
  const float* mb_b    = (const float*)d_in[6];
  const float* mod_w   = (const float*)d_in[7];
  const float* mod_b   = (const float*)d_in[8];
  const float* cluster = (const float*)d_in[9];
  const float* gate    = (const float*)d_in[10];
  const float* tmpr    = (const float*)d_in[11];
  const float* nw      = (const float*)d_in[12];
  const float* fb      = (const float*)d_in[13];
  float* out = (float*)d_out;
  char* ws = (char*)d_ws;

  __hip_bfloat16* xs   = (__hip_bfloat16*)(ws + O_XS);
  __hip_bfloat16* out1 = (__hip_bfloat16*)(ws + O_OUT1);
  __hip_bfloat16* wrt  = (__hip_bfloat16*)(ws + O_WRT);
  __hip_bfloat16* wb   = (__hip_bfloat16*)(ws + O_WB);
  float* pgram = (float*)(ws + O_PG);
  float* wsq = (float*)(ws + O_WSQ);
  float* cl  = (float*)(ws + O_CL);
  float* gr  = (float*)(ws + O_GR);
  float* sb  = (float*)(ws + O_SB);
  float* st0 = (float*)(ws + O_ST0);
  float* sts = (float*)(ws + O_STS);
  float* st2 = (float*)(ws + O_ST2);
  float* wni = (float*)(ws + O_WNI);
  float* dm  = (float*)(ws + O_DM);
  float* accs = (float*)(ws + O_ACC);

  hipMemsetAsync(xs, 0, 9469952, stream);
  hipMemsetAsync(accs, 0, 256, stream);

  k_prep<<<1, 512, 0, stream>>>(cluster, tmpr, style, mb_w, mb_b, cl, gr, sb);
  k_st0<<<NB, 512, 0, stream>>>(style, mod_w, mod_b, st0);
  k_stylemix<<<NB, 512, 0, stream>>>(st0, gr, sb, sts, st2);
  k_wsq<<<512, 512, 0, stream>>>(W, wsq, wni);
  k_demod<<<NB, 512, 0, stream>>>(st2, wsq, dm);
  k_losses<<<512, 256, 0, stream>>>(co, cl, gate, accs);
  k_fin<<<1, 1, 0, stream>>>(accs, out + OUT_L);
  k_wreorg<<<512, 512, 0, stream>>>(W, wrt);
  k_wbf<<<2304, 256, 0, stream>>>(W, (unsigned short*)wb);
  k_xsprep<<<dim3(NB, 16, 8), 256, 0, stream>>>(x, sts, xs);
  k_convmfma<<<dim3(69, 4, 4), 256, 0, stream>>>(xs, wrt, out1);
  k_gram<<<dim3(4, 4, 8), 256, 0, stream>>>(wb, pgram);
  k_gramred<<<1024, 256, 0, stream>>>(pgram, wni, out + OUT_CO);
  k_blur<<<4096, 256, 0, stream>>>(out1, dm, noise, nw, fb, out);
}

// Round 3
// 369.974 us; speedup vs baseline: 2.4255x; 1.0508x over previous
//
#include <hip/hip_runtime.h>
#include <hip/hip_bf16.h>

#define NB 8
#define LIN_SCALE 0.044194173824159216f
#define SCALE 0.014731391274719736f

typedef __attribute__((ext_vector_type(8))) short short8;
typedef __attribute__((ext_vector_type(4))) float floatx4;

// ---------------- workspace layout (bytes) ----------------
static constexpr size_t O_XS   = 0;                   // 8*34*34*512 bf16 = 9,469,952 (zero-padded NHWC modulated x)
static constexpr size_t O_OUT1 = 9469952;             // parity planes bf16: 34,611,200
static constexpr size_t O_WRT  = 44081152;            // 9*512*512 bf16 wrt[tap][o][i]
static constexpr size_t O_WB   = 48799744;            // 512*4608 bf16 wb[o][k]
static constexpr size_t O_PG   = 53518336;            // 8*512*512 f32 gram partials
static constexpr size_t O_WSQ  = 61906944;            // 512*512 f32
static constexpr size_t O_CL   = 62955520;            // 16*512 f32
static constexpr size_t O_GR   = O_CL + 32768;
static constexpr size_t O_SB   = O_GR + 32768;
static constexpr size_t O_STS  = O_SB + 1024;
static constexpr size_t O_ST2  = O_STS + 16384;
static constexpr size_t O_WNI  = O_ST2 + 16384;
static constexpr size_t O_DM   = O_WNI + 2048;
static constexpr size_t O_ACC  = O_DM + 16384;

static constexpr size_t OUT_CO = 16777216;            // d_out offset of co_out
static constexpr size_t OUT_L  = 17039360;            // d_out offset of losses

// parity-class tables for the transposed conv (gather form, wf[k]=W[2-k] folded)
__device__ const int c_ylim[4] = {33,33,32,32};
__device__ const int c_xlim[4] = {33,32,33,32};
__device__ const int c_ntap[4] = {4,2,2,1};
__device__ const int c_tap0[4] = {0,4,6,8};
__device__ const int c_dy[9] = {-1,-1,0,0, -1,0, 0,0, 0};
__device__ const int c_dx[9] = {-1,0,-1,0, 0,0, -1,0, 0};
__device__ const int c_ky[9] = {2,2,0,0, 2,0, 1,1, 1};
__device__ const int c_kx[9] = {2,0,2,0, 1,1, 2,0, 1};
__device__ const long c_poff[4] = {0, 4460544, 8785920, 13111296};

__device__ __forceinline__ float wave_red(float v) {
#pragma unroll
  for (int s = 32; s > 0; s >>= 1) v += __shfl_down(v, s);
  return v;
}

__device__ __forceinline__ void gl_lds16(const void* g, void* l) {
  __builtin_amdgcn_global_load_lds((const __attribute__((address_space(1))) void*)g,
                                   (__attribute__((address_space(3))) void*)l, 16, 0, 0);
}

__device__ __forceinline__ float bfu(unsigned short u) {
  union { float f; unsigned u32; } c; c.u32 = ((unsigned)u) << 16; return c.f;
}

// ---------------- small kernels ----------------

__global__ __launch_bounds__(512) void k_prep(const float* __restrict__ cluster,
    const float* __restrict__ tmpr, const float* __restrict__ style,
    const float* __restrict__ mb_w, const float* __restrict__ mb_b,
    float* __restrict__ cl, float* __restrict__ gr, float* __restrict__ sb) {
  int c = threadIdx.x;
  float t = 5.f / (1.f + expf(-tmpr[0]));
  float v[16];
  float m = -1e30f;
#pragma unroll
  for (int g = 0; g < 16; g++) { v[g] = t * cluster[g*512 + c]; m = fmaxf(m, v[g]); }
  float s = 0.f;
#pragma unroll
  for (int g = 0; g < 16; g++) { v[g] = expf(v[g] - m); s += v[g]; }
  float inv = 1.f / s;
  float clv[16];
  float m2 = -1e30f;
#pragma unroll
  for (int g = 0; g < 16; g++) { clv[g] = v[g]*inv; cl[g*512 + c] = clv[g]; m2 = fmaxf(m2, 500.f*clv[g]); }
  float s2 = 0.f; float e2[16];
#pragma unroll
  for (int g = 0; g < 16; g++) { e2[g] = expf(500.f*clv[g] - m2); s2 += e2[g]; }
  float i2 = 1.f / s2;
#pragma unroll
  for (int g = 0; g < 16; g++) gr[g*512 + c] = rintf(e2[g]*i2) + 1e-6f;
  // style_base: wave-cooperative dots (coalesced along d)
  int wv = c >> 6, lane = c & 63;
#pragma unroll
  for (int task = wv; task < 128; task += 8) {
    int b = task >> 4, g = task & 15;
    const float* s1 = style + b*1024;
    const float* mw = mb_w + g*512;
    float acc = 0.f;
#pragma unroll
    for (int it = 0; it < 8; it++) acc = fmaf(s1[lane + 64*it], mw[lane + 64*it], acc);
    acc = wave_red(acc);
    if (lane == 0) sb[b*16 + g] = acc*LIN_SCALE + mb_b[g];
  }
}

// fused: st0 (wave-GEMV) + group-norm style mixing
__global__ __launch_bounds__(512) void k_style(const float* __restrict__ style,
    const float* __restrict__ mod_w, const float* __restrict__ mod_b,
    const float* __restrict__ gr, const float* __restrict__ sb,
    float* __restrict__ sts, float* __restrict__ st2) {
  int b = blockIdx.x, tid = threadIdx.x;
  __shared__ float s2s[512];
  __shared__ float st0s[512];
  s2s[tid] = style[b*1024 + 512 + tid];
  __syncthreads();
  int wv = tid >> 6, lane = tid & 63;
  for (int cc = 0; cc < 64; cc++) {
    int c = wv*64 + cc;
    const float* mw = mod_w + (size_t)c*512;
    float acc = 0.f;
#pragma unroll
    for (int it = 0; it < 8; it++) acc = fmaf(mw[lane + 64*it], s2s[lane + 64*it], acc);
    acc = wave_red(acc);
    if (lane == 0) st0s[c] = acc*LIN_SCALE + mod_b[c];
  }
  __syncthreads();
  int c = tid;
  float s = st0s[c];
  float grv[16];
#pragma unroll
  for (int g = 0; g < 16; g++) grv[g] = gr[g*512 + c];
  __shared__ float red[16][8];
  __shared__ float inv[16];
  __shared__ float sbb[16];
#pragma unroll
  for (int g = 0; g < 16; g++) {
    float v = grv[g]*s; v *= v;
    v = wave_red(v);
    if (lane == 0) red[g][wv] = v;
  }
  if (c < 16) sbb[c] = sb[b*16 + c];
  __syncthreads();
  if (c < 16) {
    float tt = 0.f;
#pragma unroll
    for (int w = 0; w < 8; w++) tt += red[c][w];
    inv[c] = 1.f / fmaxf(sqrtf(tt), 1e-12f);
  }
  __syncthreads();
  float f = 0.f;
#pragma unroll
  for (int g = 0; g < 16; g++) f += grv[g]*inv[g]*sbb[g];
  float sn = s*f;
  sts[b*512 + c] = sn*SCALE;
  st2[b*512 + c] = sn*sn;
}

// fused W processing: wsq + wni + wrt + wb, W read once through LDS
__global__ __launch_bounds__(512) void k_wproc(const float* __restrict__ W,
    float* __restrict__ wsq, float* __restrict__ wni,
    __hip_bfloat16* __restrict__ wrt, __hip_bfloat16* __restrict__ wb) {
  const int o = blockIdx.x, tid = threadIdx.x;
  __shared__ float wrow[4608];
  __shared__ float r8[8];
  for (int j = tid; j < 4608; j += 512) wrow[j] = W[(size_t)o*4608 + j];
  __syncthreads();
  float s = 0.f;
#pragma unroll
  for (int k = 0; k < 9; k++) { float w = wrow[tid*9 + k]; s = fmaf(w, w, s); }
  wsq[o*512 + tid] = s;
  float t = wave_red(s);
  if ((tid & 63) == 0) r8[tid >> 6] = t;
#pragma unroll
  for (int tp = 0; tp < 9; tp++)
    wrt[((size_t)tp*512 + o)*512 + tid] = __float2bfloat16(wrow[tid*9 + c_ky[tp]*3 + c_kx[tp]]);
  for (int j = tid; j < 4608; j += 512) wb[(size_t)o*4608 + j] = __float2bfloat16(wrow[j]);
  __syncthreads();
  if (tid == 0) {
    float tt = 0.f;
#pragma unroll
    for (int w = 0; w < 8; w++) tt += r8[w];
    wni[o] = 1.f / fmaxf(sqrtf(tt), 1e-12f);
  }
}

// demod: wave-GEMV over wsq rows (coalesced along i)
__global__ __launch_bounds__(256) void k_demod(const float* __restrict__ st2,
    const float* __restrict__ wsq, float* __restrict__ dm) {
  const int b = blockIdx.x >> 3, oc = blockIdx.x & 7;
  const int tid = threadIdx.x;
  __shared__ float s2s[512];
  s2s[tid] = st2[b*512 + tid];
  s2s[tid + 256] = st2[b*512 + 256 + tid];
  __syncthreads();
  const int wv = tid >> 6, lane = tid & 63;
#pragma unroll
  for (int rr = 0; rr < 16; rr++) {
    const int o = oc*64 + wv*16 + rr;
    const float* wp = wsq + (size_t)o*512;
    float acc = 0.f;
#pragma unroll
    for (int it = 0; it < 8; it++) acc = fmaf(wp[lane + 64*it], s2s[lane + 64*it], acc);
    acc = wave_red(acc);
    if (lane == 0) dm[b*512 + o] = rsqrtf((1.0f/4608.0f)*acc + 1e-8f);
  }
}

__global__ __launch_bounds__(256) void k_losses(const float* __restrict__ co,
    const float* __restrict__ cl, const float* __restrict__ gate, float* __restrict__ accs) {
  int i = blockIdx.x;
  float gg = 1.f / (1.f + expf(-gate[0]));
  float cli[16];
#pragma unroll
  for (int k = 0; k < 16; k++) cli[k] = cl[k*512 + i];
  float p1 = 0.f, p2 = 0.f;
  for (int j = threadIdx.x; j < 512; j += 256) {
    float d = 0.f;
#pragma unroll
    for (int k = 0; k < 16; k++) d = fmaf(cli[k], cl[k*512 + j], d);
    float S = 1.f / (1.f + expf(-50.f*(co[i*512 + j] - gg)));
    float e = d - S;
    p1 = fmaf(e, e, p1); p2 += S;
  }
  p1 = wave_red(p1); p2 = wave_red(p2);
  if ((threadIdx.x & 63) == 0) { atomicAdd(&accs[0], p1); atomicAdd(&accs[1], p2); }
}

__global__ void k_fin(const float* __restrict__ accs, float* __restrict__ out_tail) {
  float d = 16384.f - accs[1];
  out_tail[0] = accs[0];
  out_tail[1] = d*d;
}

// xs[b][y+1][x+1][i] = bf16(x[b][i][y][x] * sts[b][i])  (NHWC, zero ring from memset)
__global__ __launch_bounds__(256) void k_xsprep(const float* __restrict__ x,
    const float* __restrict__ sts, __hip_bfloat16* __restrict__ xs) {
  int b = blockIdx.x;
  int p0 = blockIdx.y * 64;
  int i0 = blockIdx.z * 64;
  __shared__ float L[64][65];
  int tid = threadIdx.x;
  int lp = tid & 63, li = tid >> 6;
  const float* xp = x + ((size_t)b*512 + i0)*1024 + p0;
#pragma unroll
  for (int ii = 0; ii < 16; ii++) {
    int i = li + 4*ii;
    L[i][lp] = xp[(size_t)i*1024 + lp];
  }
  __syncthreads();
  int iw = tid & 63, pw = tid >> 6;
  float sv = sts[b*512 + i0 + iw];
#pragma unroll
  for (int pp = 0; pp < 16; pp++) {
    int pix = p0 + pw + 4*pp;
    int y = pix >> 5, xq = pix & 31;
    xs[(((size_t)b*34 + (y+1))*34 + (xq+1))*512 + i0 + iw] = __float2bfloat16(L[iw][pw + 4*pp] * sv);
  }
}

// ---------------- MFMA transposed-conv GEMM ----------------
// XOR chunk swizzle: LDS slot (row, c) holds global chunk c^(row&3); frag reads use quad^(row&3).
__global__ __launch_bounds__(256, 4) void k_convmfma(
    const __hip_bfloat16* __restrict__ xs, const __hip_bfloat16* __restrict__ wrt,
    __hip_bfloat16* __restrict__ out1) {
  const int cls = blockIdx.z;
  const int xlim = c_xlim[cls];
  const int npix = c_ylim[cls] * xlim;
  const int M = NB * npix;
  const int m0 = blockIdx.x * 128;
  if (m0 >= M) return;
  const int n0 = blockIdx.y * 128;
  const int t0 = c_tap0[cls];
  const int ntap = c_ntap[cls];

  __shared__ __hip_bfloat16 smem[17408];  // A[128][32] @0, B[128][32] @4096; epilogue Ct[128][136]

  const int tid = threadIdx.x;
  long abase[2]; long bbase[2]; int ldso[2];
#pragma unroll
  for (int r = 0; r < 2; r++) {
    const int idx = r * 256 + tid;
    const int row = idx >> 2, kc = ((idx & 3) ^ (row & 3)) << 3;  // swizzled source chunk
    int rm = m0 + row; if (rm >= M) rm = 0;
    const int b = rm / npix; const int rem = rm - b * npix;
    const int yy = rem / xlim; const int xx = rem - yy * xlim;
    abase[r] = ((long)(b * 34 + yy + 1) * 34 + (xx + 1)) * 512 + kc;
    bbase[r] = ((long)(t0 * 512 + n0 + row)) * 512 + kc;
    ldso[r] = idx << 3;
  }

  const int lane = tid & 63;
  const int wv = tid >> 6;
  const int wm = (wv >> 1) << 6, wn = (wv & 1) << 6;
  const int col16 = lane & 15, quad = lane >> 4;
  const int sq = (quad ^ (col16 & 3)) << 3;  // swizzled frag chunk

  int aoff[4], boff[4];
#pragma unroll
  for (int t = 0; t < 4; t++) {
    aoff[t] = (wm + t * 16 + col16) * 32 + sq;
    boff[t] = 4096 + (wn + t * 16 + col16) * 32 + sq;
  }

  floatx4 acc[4][4];
#pragma unroll
  for (int i = 0; i < 4; i++)
#pragma unroll
    for (int j = 0; j < 4; j++) acc[i][j] = (floatx4){0.f, 0.f, 0.f, 0.f};

  for (int tp = 0; tp < ntap; tp++) {
    const int tap = t0 + tp;
    const long adel = (long)((c_dy[tap] * 34 + c_dx[tap]) * 512);
    const long bdel = (long)tp << 18;
    for (int ks = 0; ks < 16; ks++) {
      const int kk = ks << 5;
#pragma unroll
      for (int r = 0; r < 2; r++) {
        gl_lds16(xs + (abase[r] + adel + kk), smem + ldso[r]);
        gl_lds16(wrt + (bbase[r] + bdel + kk), smem + 4096 + ldso[r]);
      }
      __syncthreads();
      short8 af[4], bf[4];
#pragma unroll
      for (int t = 0; t < 4; t++) {
        af[t] = *(const short8*)(smem + aoff[t]);
        bf[t] = *(const short8*)(smem + boff[t]);
      }
#pragma unroll
      for (int i = 0; i < 4; i++)
#pragma unroll
        for (int j = 0; j < 4; j++)
          acc[i][j] = __builtin_amdgcn_mfma_f32_16x16x32_bf16(af[i], bf[j], acc[i][j], 0, 0, 0);
      __syncthreads();
    }
  }

  // transpose C through LDS: Ct[n][136]
#pragma unroll
  for (int i = 0; i < 4; i++) {
    const int mrow = wm + i * 16 + (quad << 2);
#pragma unroll
    for (int j = 0; j < 4; j++) {
      const int ncol = wn + j * 16 + col16;
#pragma unroll
      for (int r = 0; r < 4; r++)
        smem[ncol * 136 + mrow + r] = __float2bfloat16(acc[i][j][r]);
    }
  }
  __syncthreads();

  __hip_bfloat16* plane = out1 + c_poff[cls];
#pragma unroll
  for (int it = 0; it < 8; it++) {
    const int c = it * 256 + tid;
    const int o = c >> 4, ml = (c & 15) << 3;
    const int mg = m0 + ml;
    if (mg < M) {
      const ushort4 v = *(const ushort4*)(smem + o * 136 + ml);
      *(ushort4*)(plane + (long)(n0 + o) * M + mg) = v;
    }
  }
}

// ---------------- gram via MFMA, split-K=8 ----------------
__global__ __launch_bounds__(256, 4) void k_gram(const __hip_bfloat16* __restrict__ wb,
                                                 float* __restrict__ pgram) {
  const int m0 = blockIdx.x * 128, n0 = blockIdx.y * 128;
  const long kz = (long)blockIdx.z * 576;
  __shared__ __hip_bfloat16 smem[8192];
  const int tid = threadIdx.x;
  long abase[2], bbase[2]; int ldso[2];
#pragma unroll
  for (int r = 0; r < 2; r++) {
    const int idx = r * 256 + tid;
    const int row = idx >> 2, kc = ((idx & 3) ^ (row & 3)) << 3;
    abase[r] = (long)(m0 + row) * 4608 + kz + kc;
    bbase[r] = (long)(n0 + row) * 4608 + kz + kc;
    ldso[r] = idx << 3;
  }
  const int lane = tid & 63, wv = tid >> 6;
  const int wm = (wv >> 1) << 6, wn = (wv & 1) << 6;
  const int col16 = lane & 15, quad = lane >> 4;
  const int sq = (quad ^ (col16 & 3)) << 3;
  int aoff[4], boff[4];
#pragma unroll
  for (int t = 0; t < 4; t++) {
    aoff[t] = (wm + t * 16 + col16) * 32 + sq;
    boff[t] = 4096 + (wn + t * 16 + col16) * 32 + sq;
  }
  floatx4 acc[4][4];
#pragma unroll
  for (int i = 0; i < 4; i++)
#pragma unroll
    for (int j = 0; j < 4; j++) acc[i][j] = (floatx4){0.f, 0.f, 0.f, 0.f};
  for (int ks = 0; ks < 18; ks++) {
    const int kk = ks << 5;
#pragma unroll
    for (int r = 0; r < 2; r++) {
      gl_lds16(wb + (abase[r] + kk), smem + ldso[r]);
      gl_lds16(wb + (bbase[r] + kk), smem + 4096 + ldso[r]);
    }
    __syncthreads();
    short8 af[4], bf[4];
#pragma unroll
    for (int t = 0; t < 4; t++) {
      af[t] = *(const short8*)(smem + aoff[t]);
      bf[t] = *(const short8*)(smem + boff[t]);
    }
#pragma unroll
    for (int i = 0; i < 4; i++)
#pragma unroll
      for (int j = 0; j < 4; j++)
        acc[i][j] = __builtin_amdgcn_mfma_f32_16x16x32_bf16(af[i], bf[j], acc[i][j], 0, 0, 0);
    __syncthreads();
  }
  float* pg = pgram + (size_t)blockIdx.z * 262144;
#pragma unroll
  for (int i = 0; i < 4; i++)
#pragma unroll
    for (int j = 0; j < 4; j++) {
      const int m = m0 + wm + i * 16 + (quad << 2);
      const int n = n0 + wn + j * 16 + col16;
#pragma unroll
      for (int r = 0; r < 4; r++) pg[(size_t)(m + r) * 512 + n] = acc[i][j][r];
    }
}

__global__ __launch_bounds__(256) void k_gramred(const float* __restrict__ pgram,
    const float* __restrict__ wni, float* __restrict__ co_out) {
  const int idx = blockIdx.x * 256 + threadIdx.x;
  float s = 0.f;
#pragma unroll
  for (int z = 0; z < 8; z++) s += pgram[(size_t)z * 262144 + idx];
  const int m = idx >> 9, n = idx & 511;
  co_out[idx] = s * wni[m] * wni[n];
}

// ---------------- blur: LDS-staged 65x65 grid, branch-free inner loads ----------------
__global__ __launch_bounds__(256) void k_blur(const __hip_bfloat16* __restrict__ out1,
    const float* __restrict__ dm, const float* __restrict__ noise,
    const float* __restrict__ nw, const float* __restrict__ fb, float* __restrict__ out) {
  const int bo = blockIdx.x;
  const int b = bo >> 9, o = bo & 511;
  __shared__ unsigned short L[65 * 68];   // [m][q+1], cols 0 and 66 are zero guards
  const int tid = threadIdx.x;
  const unsigned short* p0 = (const unsigned short*)out1 + 0        + (long)o * 8712 + b * 1089;
  const unsigned short* p1 = (const unsigned short*)out1 + 4460544  + (long)o * 8448 + b * 1056;
  const unsigned short* p2 = (const unsigned short*)out1 + 8785920  + (long)o * 8448 + b * 1056;
  const unsigned short* p3 = (const unsigned short*)out1 + 13111296 + (long)o * 8192 + b * 1024;
  for (int m = tid; m < 65; m += 256) { L[m*68 + 0] = 0; L[m*68 + 66] = 0; }
  for (int e = tid; e < 1089; e += 256) { int y = e / 33, x = e - 33*y; L[(2*y)*68 + 2*x + 1] = p0[e]; }
  for (int e = tid; e < 1056; e += 256) { int y = e >> 5, x = e & 31;   L[(2*y)*68 + 2*x + 2] = p1[e]; }
  for (int e = tid; e < 1056; e += 256) { int y = e / 33, x = e - 33*y; L[(2*y+1)*68 + 2*x + 1] = p2[e]; }
  for (int e = tid; e < 1024; e += 256) { int y = e >> 5, x = e & 31;   L[(2*y+1)*68 + 2*x + 2] = p3[e]; }
  __syncthreads();
  const float dmv = dm[bo];
  const float nwv = nw[0];
  const float bv = fb[o];
  const int Q = tid & 63;
  const int qy = tid >> 6;
  const int mbase = 16 * qy - 1;
  float hs[18];
#pragma unroll
  for (int rm = 0; rm < 18; rm++) {
    const int m = mbase + rm;
    float s = 0.f;
    if (m >= 0 && m <= 64) {
      const unsigned short* row = L + m*68 + Q;
      s = 0.25f * (bfu(row[0]) + bfu(row[3])) + 0.75f * (bfu(row[1]) + bfu(row[2]));
    }
    hs[rm] = s;
  }
  float* op = out + ((size_t)bo << 12);
  const float* npl = noise + ((size_t)b << 12);
#pragma unroll
  for (int pp = 0; pp < 16; pp++) {
    const int P = 16 * qy + pp;
    float s = 0.25f * (hs[pp] + hs[pp + 3]) + 0.75f * (hs[pp + 1] + hs[pp + 2]);
    float v = fmaf(dmv, s, fmaf(nwv, npl[P * 64 + Q], bv));
    v = (v >= 0.f ? v : 0.2f * v) * 1.4142135623730951f;
    op[P * 64 + Q] = v;
  }
}

extern "C" void kernel_launch(void* const* d_in, const int* in_sizes, int n_in,
                              void* d_out, int out_size, void* d_ws, size_t ws_size,
                              hipStream_t stream) {
  const float* x       = (const float*)d_in[0];
  const float* co      = (const float*)d_in[1];
  const float* style   = (const float*)d_in[2];
  const float* noise   = (const float*)d_in[3];
  const float* W       = (const float*)d_in[4];
  const float* mb_w    = (const float*)d_in[5];
  const float* mb_b    = (const float*)d_in[6];
  const float* mod_w   = (const float*)d_in[7];
  const float* mod_b   = (const float*)d_in[8];
  const float* cluster = (const float*)d_in[9];
  const float* gate    = (const float*)d_in[10];
  const float* tmpr    = (const float*)d_in[11];
  const float* nw      = (const float*)d_in[12];
  const float* fb      = (const float*)d_in[13];
  float* out = (float*)d_out;
  char* ws = (char*)d_ws;

  __hip_bfloat16* xs   = (__hip_bfloat16*)(ws + O_XS);
  __hip_bfloat16* out1 = (__hip_bfloat16*)(ws + O_OUT1);
  __hip_bfloat16* wrt  = (__hip_bfloat16*)(ws + O_WRT);
  __hip_bfloat16* wb   = (__hip_bfloat16*)(ws + O_WB);
  float* pgram = (float*)(ws + O_PG);
  float* wsq = (float*)(ws + O_WSQ);
  float* cl  = (float*)(ws + O_CL);
  float* gr  = (float*)(ws + O_GR);
  float* sb  = (float*)(ws + O_SB);
  float* sts = (float*)(ws + O_STS);
  float* st2 = (float*)(ws + O_ST2);
  float* wni = (float*)(ws + O_WNI);
  float* dm  = (float*)(ws + O_DM);
  float* accs = (float*)(ws + O_ACC);

  hipMemsetAsync(xs, 0, 9469952, stream);
  hipMemsetAsync(accs, 0, 256, stream);

  k_prep<<<1, 512, 0, stream>>>(cluster, tmpr, style, mb_w, mb_b, cl, gr, sb);
  k_style<<<NB, 512, 0, stream>>>(style, mod_w, mod_b, gr, sb, sts, st2);
  k_wproc<<<512, 512, 0, stream>>>(W, wsq, wni, wrt, wb);
  k_demod<<<64, 256, 0, stream>>>(st2, wsq, dm);
  k_losses<<<512, 256, 0, stream>>>(co, cl, gate, accs);
  k_fin<<<1, 1, 0, stream>>>(accs, out + OUT_L);
  k_xsprep<<<dim3(NB, 16, 8), 256, 0, stream>>>(x, sts, xs);
  k_convmfma<<<dim3(69, 4, 4), 256, 0, stream>>>(xs, wrt, out1);
  k_gram<<<dim3(4, 4, 8), 256, 0, stream>>>(wb, pgram);
  k_gramred<<<1024, 256, 0, stream>>>(pgram, wni, out + OUT_CO);
  k_blur<<<4096, 256, 0, stream>>>(out1, dm, noise, nw, fb, out);
}

// Round 4
// 327.325 us; speedup vs baseline: 2.7416x; 1.1303x over previous
//
#include <hip/hip_runtime.h>
#include <hip/hip_bf16.h>

#define NB 8
#define LIN_SCALE 0.044194173824159216f
#define SCALE 0.014731391274719736f

typedef __attribute__((ext_vector_type(8))) short short8;
typedef __attribute__((ext_vector_type(4))) float floatx4;

// ---------------- workspace layout (bytes) ----------------
static constexpr size_t O_XS   = 0;                   // 8*34*34*512 bf16 (zero-padded NHWC modulated x)
static constexpr size_t O_OUT1 = 9469952;             // parity planes bf16: 34,611,200
static constexpr size_t O_WRT  = 44081152;            // 9*512*512 bf16 wrt[tap][o][i]
static constexpr size_t O_WB   = 48799744;            // 512*4608 bf16 wb[o][k]
static constexpr size_t O_PG   = 53518336;            // 8*512*512 f32 gram partials
static constexpr size_t O_WSQ  = 61906944;            // 512*512 f32
static constexpr size_t O_CL   = 62955520;            // 16*512 f32
static constexpr size_t O_GR   = O_CL + 32768;
static constexpr size_t O_SB   = O_GR + 32768;
static constexpr size_t O_ST0  = O_SB + 1024;
static constexpr size_t O_STS  = O_ST0 + 16384;
static constexpr size_t O_ST2  = O_STS + 16384;
static constexpr size_t O_WNI  = O_ST2 + 16384;
static constexpr size_t O_DM   = O_WNI + 2048;
static constexpr size_t O_ACC  = O_DM + 16384;

static constexpr size_t OUT_CO = 16777216;            // d_out offset of co_out
static constexpr size_t OUT_L  = 17039360;            // d_out offset of losses

// parity-class tables for the transposed conv (gather form, wf[k]=W[2-k] folded)
__device__ const int c_ylim[4] = {33,33,32,32};
__device__ const int c_xlim[4] = {33,32,33,32};
__device__ const int c_ntap[4] = {4,2,2,1};
__device__ const int c_tap0[4] = {0,4,6,8};
__device__ const int c_nmb[4]  = {69,66,66,64};       // ceil(M/128)
__device__ const int c_dy[9] = {-1,-1,0,0, -1,0, 0,0, 0};
__device__ const int c_dx[9] = {-1,0,-1,0, 0,0, -1,0, 0};
__device__ const int c_ky[9] = {2,2,0,0, 2,0, 1,1, 1};
__device__ const int c_kx[9] = {2,0,2,0, 1,1, 2,0, 1};
__device__ const long c_poff[4] = {0, 4460544, 8785920, 13111296};

__device__ __forceinline__ float wave_red(float v) {
#pragma unroll
  for (int s = 32; s > 0; s >>= 1) v += __shfl_down(v, s);
  return v;
}

__device__ __forceinline__ void gl_lds16(const void* g, void* l) {
  __builtin_amdgcn_global_load_lds((const __attribute__((address_space(1))) void*)g,
                                   (__attribute__((address_space(3))) void*)l, 16, 0, 0);
}

__device__ __forceinline__ unsigned short bf16b(float f) {
  union { __hip_bfloat16 h; unsigned short u; } cv;
  cv.h = __float2bfloat16(f);
  return cv.u;
}

__device__ __forceinline__ float bfu(unsigned short u) {
  union { float f; unsigned u32; } c; c.u32 = ((unsigned)u) << 16; return c.f;
}

// ---------------- K1: cl/gr/sb prep + accs zero (1 block) ----------------
__global__ __launch_bounds__(512) void k_prep(const float* __restrict__ cluster,
    const float* __restrict__ tmpr, const float* __restrict__ style,
    const float* __restrict__ mb_w, const float* __restrict__ mb_b,
    float* __restrict__ cl, float* __restrict__ gr, float* __restrict__ sb,
    float* __restrict__ accs) {
  int c = threadIdx.x;
  if (c < 2) accs[c] = 0.f;
  float t = 5.f / (1.f + expf(-tmpr[0]));
  float v[16];
  float m = -1e30f;
#pragma unroll
  for (int g = 0; g < 16; g++) { v[g] = t * cluster[g*512 + c]; m = fmaxf(m, v[g]); }
  float s = 0.f;
#pragma unroll
  for (int g = 0; g < 16; g++) { v[g] = expf(v[g] - m); s += v[g]; }
  float inv = 1.f / s;
  float clv[16];
  float m2 = -1e30f;
#pragma unroll
  for (int g = 0; g < 16; g++) { clv[g] = v[g]*inv; cl[g*512 + c] = clv[g]; m2 = fmaxf(m2, 500.f*clv[g]); }
  float s2 = 0.f; float e2[16];
#pragma unroll
  for (int g = 0; g < 16; g++) { e2[g] = expf(500.f*clv[g] - m2); s2 += e2[g]; }
  float i2 = 1.f / s2;
#pragma unroll
  for (int g = 0; g < 16; g++) gr[g*512 + c] = rintf(e2[g]*i2) + 1e-6f;
  int wv = c >> 6, lane = c & 63;
#pragma unroll
  for (int task = wv; task < 128; task += 8) {
    int b = task >> 4, g = task & 15;
    const float* s1 = style + b*1024;
    const float* mw = mb_w + g*512;
    float acc = 0.f;
#pragma unroll
    for (int it = 0; it < 8; it++) acc = fmaf(s1[lane + 64*it], mw[lane + 64*it], acc);
    acc = wave_red(acc);
    if (lane == 0) sb[b*16 + g] = acc*LIN_SCALE + mb_b[g];
  }
}

// ---------------- K2: wproc(512) + st0(64) + losses(512), 1088 blocks ----------------
__global__ __launch_bounds__(256) void k_big1(const float* __restrict__ W,
    float* __restrict__ wsq, float* __restrict__ wni,
    __hip_bfloat16* __restrict__ wrt, unsigned short* __restrict__ wb,
    const float* __restrict__ style, const float* __restrict__ mod_w,
    const float* __restrict__ mod_b, float* __restrict__ st0,
    const float* __restrict__ co, const float* __restrict__ cl,
    const float* __restrict__ gate, float* __restrict__ accs) {
  __shared__ float sh[4608];
  __shared__ float r4[4];
  const int bid = blockIdx.x, tid = threadIdx.x;
  const int lane = tid & 63, wv = tid >> 6;
  if (bid < 512) {
    const int o = bid;
    for (int j = tid; j < 4608; j += 256) sh[j] = W[(size_t)o*4608 + j];
    __syncthreads();
    float tot = 0.f;
#pragma unroll
    for (int half = 0; half < 2; half++) {
      const int i = tid + half*256;
      float s = 0.f;
#pragma unroll
      for (int k = 0; k < 9; k++) { float w = sh[i*9 + k]; s = fmaf(w, w, s); }
      wsq[o*512 + i] = s; tot += s;
#pragma unroll
      for (int tp = 0; tp < 9; tp++)
        wrt[((size_t)tp*512 + o)*512 + i] = __float2bfloat16(sh[i*9 + c_ky[tp]*3 + c_kx[tp]]);
    }
    for (int j = tid; j < 4608; j += 256) wb[(size_t)o*4608 + j] = bf16b(sh[j]);
    tot = wave_red(tot);
    if (lane == 0) r4[wv] = tot;
    __syncthreads();
    if (tid == 0) wni[o] = 1.f / fmaxf(sqrtf(r4[0]+r4[1]+r4[2]+r4[3]), 1e-12f);
  } else if (bid < 576) {
    const int b = (bid - 512) >> 3, oc = (bid - 512) & 7;
    sh[tid] = style[b*1024 + 512 + tid];
    sh[tid + 256] = style[b*1024 + 768 + tid];
    __syncthreads();
#pragma unroll
    for (int rr = 0; rr < 16; rr++) {
      const int c = oc*64 + wv*16 + rr;
      const float* mw = mod_w + (size_t)c*512;
      float acc = 0.f;
#pragma unroll
      for (int it = 0; it < 8; it++) acc = fmaf(mw[lane + 64*it], sh[lane + 64*it], acc);
      acc = wave_red(acc);
      if (lane == 0) st0[b*512 + c] = acc*LIN_SCALE + mod_b[c];
    }
  } else {
    const int i = bid - 576;
    float gg = 1.f / (1.f + expf(-gate[0]));
    float cli[16];
#pragma unroll
    for (int k = 0; k < 16; k++) cli[k] = cl[k*512 + i];
    float p1 = 0.f, p2 = 0.f;
    for (int j = tid; j < 512; j += 256) {
      float d = 0.f;
#pragma unroll
      for (int k = 0; k < 16; k++) d = fmaf(cli[k], cl[k*512 + j], d);
      float S = 1.f / (1.f + expf(-50.f*(co[i*512 + j] - gg)));
      float e = d - S;
      p1 = fmaf(e, e, p1); p2 += S;
    }
    p1 = wave_red(p1); p2 = wave_red(p2);
    if (lane == 0) { atomicAdd(&accs[0], p1); atomicAdd(&accs[1], p2); }
  }
}

// ---------------- K3: style mix (8 blocks) + fin (1 block) ----------------
__global__ __launch_bounds__(256) void k_mix(const float* __restrict__ st0,
    const float* __restrict__ gr, const float* __restrict__ sb,
    float* __restrict__ sts, float* __restrict__ st2,
    const float* __restrict__ accs, float* __restrict__ out_tail) {
  if (blockIdx.x == 8) {
    if (threadIdx.x == 0) {
      float d = 16384.f - accs[1];
      out_tail[0] = accs[0];
      out_tail[1] = d*d;
    }
    return;
  }
  const int b = blockIdx.x, tid = threadIdx.x;
  const int lane = tid & 63, wv = tid >> 6;
  float s0 = st0[b*512 + tid], s1 = st0[b*512 + 256 + tid];
  float g0[16], g1[16];
#pragma unroll
  for (int g = 0; g < 16; g++) { g0[g] = gr[g*512 + tid]; g1[g] = gr[g*512 + 256 + tid]; }
  __shared__ float red[16][4];
  __shared__ float inv[16];
  __shared__ float sbb[16];
#pragma unroll
  for (int g = 0; g < 16; g++) {
    float a = g0[g]*s0, c = g1[g]*s1;
    float p = wave_red(a*a + c*c);
    if (lane == 0) red[g][wv] = p;
  }
  if (tid < 16) sbb[tid] = sb[b*16 + tid];
  __syncthreads();
  if (tid < 16) {
    float tt = red[tid][0] + red[tid][1] + red[tid][2] + red[tid][3];
    inv[tid] = 1.f / fmaxf(sqrtf(tt), 1e-12f);
  }
  __syncthreads();
  float f0 = 0.f, f1 = 0.f;
#pragma unroll
  for (int g = 0; g < 16; g++) {
    float w = inv[g]*sbb[g];
    f0 = fmaf(g0[g], w, f0); f1 = fmaf(g1[g], w, f1);
  }
  float sn0 = s0*f0, sn1 = s1*f1;
  sts[b*512 + tid] = sn0*SCALE;        st2[b*512 + tid] = sn0*sn0;
  sts[b*512 + 256 + tid] = sn1*SCALE;  st2[b*512 + 256 + tid] = sn1*sn1;
}

// ---------------- K4: demod(64) + xsprep(1024), 1088 blocks ----------------
__global__ __launch_bounds__(256) void k_big2(const float* __restrict__ st2,
    const float* __restrict__ wsq, float* __restrict__ dm,
    const float* __restrict__ x, const float* __restrict__ sts,
    __hip_bfloat16* __restrict__ xs) {
  __shared__ float L[64*65];
  const int tid = threadIdx.x;
  const int lane = tid & 63, wv = tid >> 6;
  if (blockIdx.x < 64) {
    const int b = blockIdx.x >> 3, oc = blockIdx.x & 7;
    L[tid] = st2[b*512 + tid];
    L[tid + 256] = st2[b*512 + 256 + tid];
    __syncthreads();
#pragma unroll
    for (int rr = 0; rr < 16; rr++) {
      const int o = oc*64 + wv*16 + rr;
      const float* wp = wsq + (size_t)o*512;
      float acc = 0.f;
#pragma unroll
      for (int it = 0; it < 8; it++) acc = fmaf(wp[lane + 64*it], L[lane + 64*it], acc);
      acc = wave_red(acc);
      if (lane == 0) dm[b*512 + o] = rsqrtf((1.0f/4608.0f)*acc + 1e-8f);
    }
    return;
  }
  const int id = blockIdx.x - 64;
  const int b = id >> 7;
  const int p0 = ((id >> 3) & 15) * 64;
  const int i0 = (id & 7) * 64;
  const int lp = tid & 63, li = tid >> 6;
  const float* xp = x + ((size_t)b*512 + i0)*1024 + p0;
#pragma unroll
  for (int ii = 0; ii < 16; ii++) {
    const int i = li + 4*ii;
    L[i*65 + lp] = xp[(size_t)i*1024 + lp];
  }
  __syncthreads();
  const int iw = tid & 63, pw = tid >> 6;
  const float sv = sts[b*512 + i0 + iw];
#pragma unroll
  for (int pp = 0; pp < 16; pp++) {
    const int pix = p0 + pw + 4*pp;
    const int y = pix >> 5, xq = pix & 31;
    xs[(((size_t)b*34 + (y+1))*34 + (xq+1))*512 + i0 + iw] = __float2bfloat16(L[iw*65 + pw + 4*pp] * sv);
  }
}

// ---------------- K5: conv MFMA (1060) + gram MFMA (128), 1188 blocks ----------------
// LDS: A[128][32]bf16 @0..4095, B[128][32] @4096..8191 (elements); epilogue Ct[64][136] (17408 B total)
__global__ __launch_bounds__(256, 4) void k_mfma(
    const __hip_bfloat16* __restrict__ xs, const __hip_bfloat16* __restrict__ wrt,
    __hip_bfloat16* __restrict__ out1, const __hip_bfloat16* __restrict__ wb,
    float* __restrict__ pgram) {
  __shared__ __hip_bfloat16 smem[8704];
  const int fid = blockIdx.x;
  const int tid = threadIdx.x;
  const int lane = tid & 63, wv = tid >> 6;
  const int wm = (wv >> 1) << 6, wn = (wv & 1) << 6;
  const int col16 = lane & 15, quad = lane >> 4;

  int aoff[4], boff[4];
#pragma unroll
  for (int t = 0; t < 4; t++) {
    aoff[t] = (wm + t*16 + col16)*32 + quad*8;
    boff[t] = 4096 + (wn + t*16 + col16)*32 + quad*8;
  }
  floatx4 acc[4][4];
#pragma unroll
  for (int i = 0; i < 4; i++)
#pragma unroll
    for (int j = 0; j < 4; j++) acc[i][j] = (floatx4){0.f, 0.f, 0.f, 0.f};

  if (fid >= 276 && fid < 404) {
    // ---- gram: wn_gram @ wn_gram^T partial, split-K=8 ----
    const int g = fid - 276;
    const int m0 = (g & 3) * 128, n0 = ((g >> 2) & 3) * 128;
    const long kz = (long)(g >> 4) * 576;
    long abase[2], bbase[2]; int ldso[2];
#pragma unroll
    for (int r = 0; r < 2; r++) {
      const int idx = r*256 + tid;
      const int row = idx >> 2, kc = (idx & 3) << 3;
      abase[r] = (long)(m0 + row)*4608 + kz + kc;
      bbase[r] = (long)(n0 + row)*4608 + kz + kc;
      ldso[r] = idx << 3;
    }
    for (int ks = 0; ks < 18; ks++) {
      const int kk = ks << 5;
#pragma unroll
      for (int r = 0; r < 2; r++) {
        gl_lds16(wb + (abase[r] + kk), smem + ldso[r]);
        gl_lds16(wb + (bbase[r] + kk), smem + 4096 + ldso[r]);
      }
      __syncthreads();
      short8 af[4], bf[4];
#pragma unroll
      for (int t = 0; t < 4; t++) {
        af[t] = *(const short8*)(smem + aoff[t]);
        bf[t] = *(const short8*)(smem + boff[t]);
      }
#pragma unroll
      for (int i = 0; i < 4; i++)
#pragma unroll
        for (int j = 0; j < 4; j++)
          acc[i][j] = __builtin_amdgcn_mfma_f32_16x16x32_bf16(af[i], bf[j], acc[i][j], 0, 0, 0);
      __syncthreads();
    }
    float* pg = pgram + (size_t)(g >> 4) * 262144;
#pragma unroll
    for (int i = 0; i < 4; i++)
#pragma unroll
      for (int j = 0; j < 4; j++) {
        const int m = m0 + wm + i*16 + (quad << 2);
        const int n = n0 + wn + j*16 + col16;
#pragma unroll
        for (int r = 0; r < 4; r++) pg[(size_t)(m + r)*512 + n] = acc[i][j][r];
      }
    return;
  }

  // ---- conv ----
  int cls, id2;
  if (fid < 276)      { cls = 0; id2 = fid; }
  else if (fid < 668) { cls = 1; id2 = fid - 404; }
  else if (fid < 932) { cls = 2; id2 = fid - 668; }
  else                { cls = 3; id2 = fid - 932; }
  const int nmb = c_nmb[cls];
  const int nb = id2 / nmb, mb = id2 - nb*nmb;
  const int xlim = c_xlim[cls];
  const int npix = c_ylim[cls] * xlim;
  const int M = NB * npix;
  const int m0 = mb * 128, n0 = nb * 128;
  const int t0 = c_tap0[cls];
  const int ntap = c_ntap[cls];

  long abase[2], bbase[2]; int ldso[2];
#pragma unroll
  for (int r = 0; r < 2; r++) {
    const int idx = r*256 + tid;
    const int row = idx >> 2, kc = (idx & 3) << 3;
    int rm = m0 + row; if (rm >= M) rm = 0;
    const int b = rm / npix; const int rem = rm - b*npix;
    const int yy = rem / xlim; const int xx = rem - yy*xlim;
    abase[r] = ((long)(b*34 + yy + 1)*34 + (xx + 1))*512 + kc;
    bbase[r] = ((long)(t0*512 + n0 + row))*512 + kc;
    ldso[r] = idx << 3;
  }

  for (int tp = 0; tp < ntap; tp++) {
    const int tap = t0 + tp;
    const long adel = (long)((c_dy[tap]*34 + c_dx[tap])*512);
    const long bdel = (long)tp << 18;
    for (int ks = 0; ks < 16; ks++) {
      const int kk = ks << 5;
#pragma unroll
      for (int r = 0; r < 2; r++) {
        gl_lds16(xs + (abase[r] + adel + kk), smem + ldso[r]);
        gl_lds16(wrt + (bbase[r] + bdel + kk), smem + 4096 + ldso[r]);
      }
      __syncthreads();
      short8 af[4], bf[4];
#pragma unroll
      for (int t = 0; t < 4; t++) {
        af[t] = *(const short8*)(smem + aoff[t]);
        bf[t] = *(const short8*)(smem + boff[t]);
      }
#pragma unroll
      for (int i = 0; i < 4; i++)
#pragma unroll
        for (int j = 0; j < 4; j++)
          acc[i][j] = __builtin_amdgcn_mfma_f32_16x16x32_bf16(af[i], bf[j], acc[i][j], 0, 0, 0);
      __syncthreads();
    }
  }

  // two-pass epilogue: transpose 64 n-cols at a time through Ct[64][136]
  __hip_bfloat16* plane = out1 + c_poff[cls];
#pragma unroll
  for (int h = 0; h < 2; h++) {
    if ((wv & 1) == h) {
#pragma unroll
      for (int i = 0; i < 4; i++) {
        const int mrow = wm + i*16 + (quad << 2);
#pragma unroll
        for (int j = 0; j < 4; j++) {
          const int ncl = j*16 + col16;               // local col in [0,64)
          ushort4 v;
          v.x = bf16b(acc[i][j][0]); v.y = bf16b(acc[i][j][1]);
          v.z = bf16b(acc[i][j][2]); v.w = bf16b(acc[i][j][3]);
          *(ushort4*)(smem + ncl*136 + mrow) = v;
        }
      }
    }
    __syncthreads();
#pragma unroll
    for (int it = 0; it < 4; it++) {
      const int c = it*256 + tid;
      const int ol = c >> 4, ml = (c & 15) << 3;
      const int mg = m0 + ml;
      if (mg < M) {
        const ushort4 v = *(const ushort4*)(smem + ol*136 + ml);
        *(ushort4*)(plane + (long)(n0 + h*64 + ol)*M + mg) = v;
      }
    }
    __syncthreads();
  }
}

// ---------------- K6: gram reduce + normalize ----------------
__global__ __launch_bounds__(256) void k_gramred(const float* __restrict__ pgram,
    const float* __restrict__ wni, float* __restrict__ co_out) {
  const int i4 = blockIdx.x*256 + threadIdx.x;      // 65536 float4s
  float4 s = make_float4(0.f, 0.f, 0.f, 0.f);
#pragma unroll
  for (int z = 0; z < 8; z++) {
    const float4 v = ((const float4*)(pgram + (size_t)z*262144))[i4];
    s.x += v.x; s.y += v.y; s.z += v.z; s.w += v.w;
  }
  const float wm = wni[i4 >> 7];
  const float4 wn4 = ((const float4*)wni)[i4 & 127];
  float4 o;
  o.x = s.x*wm*wn4.x; o.y = s.y*wm*wn4.y; o.z = s.z*wm*wn4.z; o.w = s.w*wm*wn4.w;
  ((float4*)co_out)[i4] = o;
}

// ---------------- K7: blur + epilogue ----------------
__global__ __launch_bounds__(256) void k_blur(const __hip_bfloat16* __restrict__ out1,
    const float* __restrict__ dm, const float* __restrict__ noise,
    const float* __restrict__ nw, const float* __restrict__ fb, float* __restrict__ out) {
  const int bo = blockIdx.x;
  const int b = bo >> 9, o = bo & 511;
  __shared__ unsigned short L[65 * 68];   // [m][q+1], cols 0 and 66 are zero guards
  const int tid = threadIdx.x;
  const unsigned short* p0 = (const unsigned short*)out1 + 0        + (long)o * 8712 + b * 1089;
  const unsigned short* p1 = (const unsigned short*)out1 + 4460544  + (long)o * 8448 + b * 1056;
  const unsigned short* p2 = (const unsigned short*)out1 + 8785920  + (long)o * 8448 + b * 1056;
  const unsigned short* p3 = (const unsigned short*)out1 + 13111296 + (long)o * 8192 + b * 1024;
  for (int m = tid; m < 65; m += 256) { L[m*68 + 0] = 0; L[m*68 + 66] = 0; }
  for (int e = tid; e < 1089; e += 256) { int y = e / 33, x = e - 33*y; L[(2*y)*68 + 2*x + 1] = p0[e]; }
  for (int e = tid; e < 1056; e += 256) { int y = e >> 5, x = e & 31;   L[(2*y)*68 + 2*x + 2] = p1[e]; }
  for (int e = tid; e < 1056; e += 256) { int y = e / 33, x = e - 33*y; L[(2*y+1)*68 + 2*x + 1] = p2[e]; }
  for (int e = tid; e < 1024; e += 256) { int y = e >> 5, x = e & 31;   L[(2*y+1)*68 + 2*x + 2] = p3[e]; }
  __syncthreads();
  const float dmv = dm[bo];
  const float nwv = nw[0];
  const float bv = fb[o];
  const int Q = tid & 63;
  const int qy = tid >> 6;
  const int mbase = 16 * qy - 1;
  float hs[18];
#pragma unroll
  for (int rm = 0; rm < 18; rm++) {
    const int m = mbase + rm;
    float s = 0.f;
    if (m >= 0 && m <= 64) {
      const unsigned short* row = L + m*68 + Q;
      s = 0.25f * (bfu(row[0]) + bfu(row[3])) + 0.75f * (bfu(row[1]) + bfu(row[2]));
    }
    hs[rm] = s;
  }
  float* op = out + ((size_t)bo << 12);
  const float* npl = noise + ((size_t)b << 12);
#pragma unroll
  for (int pp = 0; pp < 16; pp++) {
    const int P = 16 * qy + pp;
    float s = 0.25f * (hs[pp] + hs[pp + 3]) + 0.75f * (hs[pp + 1] + hs[pp + 2]);
    float v = fmaf(dmv, s, fmaf(nwv, npl[P * 64 + Q], bv));
    v = (v >= 0.f ? v : 0.2f * v) * 1.4142135623730951f;
    op[P * 64 + Q] = v;
  }
}

extern "C" void kernel_launch(void* const* d_in, const int* in_sizes, int n_in,
                              void* d_out, int out_size, void* d_ws, size_t ws_size,
                              hipStream_t stream) {
  const float* x       = (const float*)d_in[0];
  const float* co      = (const float*)d_in[1];
  const float* style   = (const float*)d_in[2];
  const float* noise   = (const float*)d_in[3];
  const float* W       = (const float*)d_in[4];
  const float* mb_w    = (const float*)d_in[5];
  const float* mb_b    = (const float*)d_in[6];
  const float* mod_w   = (const float*)d_in[7];
  const float* mod_b   = (const float*)d_in[8];
  const float* cluster = (const float*)d_in[9];
  const float* gate    = (const float*)d_in[10];
  const float* tmpr    = (const float*)d_in[11];
  const float* nw      = (const float*)d_in[12];
  const float* fb      = (const float*)d_in[13];
  float* out = (float*)d_out;
  char* ws = (char*)d_ws;

  __hip_bfloat16* xs   = (__hip_bfloat16*)(ws + O_XS);
  __hip_bfloat16* out1 = (__hip_bfloat16*)(ws + O_OUT1);
  __hip_bfloat16* wrt  = (__hip_bfloat16*)(ws + O_WRT);
  __hip_bfloat16* wb   = (__hip_bfloat16*)(ws + O_WB);
  float* pgram = (float*)(ws + O_PG);
  float* wsq = (float*)(ws + O_WSQ);
  float* cl  = (float*)(ws + O_CL);
  float* gr  = (float*)(ws + O_GR);
  float* sb  = (float*)(ws + O_SB);
  float* st0 = (float*)(ws + O_ST0);
  float* sts = (float*)(ws + O_STS);
  float* st2 = (float*)(ws + O_ST2);
  float* wni = (float*)(ws + O_WNI);
  float* dm  = (float*)(ws + O_DM);
  float* accs = (float*)(ws + O_ACC);

  hipMemsetAsync(xs, 0, 9469952, stream);
  k_prep<<<1, 512, 0, stream>>>(cluster, tmpr, style, mb_w, mb_b, cl, gr, sb, accs);
  k_big1<<<1088, 256, 0, stream>>>(W, wsq, wni, wrt, (unsigned short*)wb,
                                   style, mod_w, mod_b, st0, co, cl, gate, accs);
  k_mix<<<9, 256, 0, stream>>>(st0, gr, sb, sts, st2, accs, out + OUT_L);
  k_big2<<<1088, 256, 0, stream>>>(st2, wsq, dm, x, sts, xs);
  k_mfma<<<1188, 256, 0, stream>>>(xs, wrt, out1, wb, pgram);
  k_gramred<<<256, 256, 0, stream>>>(pgram, wni, out + OUT_CO);
  k_blur<<<4096, 256, 0, stream>>>(out1, dm, noise, nw, fb, out);
}